// Round 3
// baseline (605.449 us; speedup 1.0000x reference)
//
#include <hip/hip_runtime.h>
#include <math.h>

#define BB 128
#define SS 1024
#define EE 2048
#define HH 300
#define AA 5
#define CC 3
#define NB 8          // softmax partial blocks per sample
#define PSTRIDE 304   // partial record: 300 acc + l + m (padded)
#define CH 16         // cone-row chunk per gather pass (worst case loops)

// ---------------- ws layout (floats) ----------------
// deg [B*S] | qbuf [B*H] | part [B*NB*PSTRIDE] | span [B*H] | zbuf [B*H] | syn [B*H]

__global__ void k_init(float* deg, float* zbuf) {
    int gid = blockIdx.x * blockDim.x + threadIdx.x;
    if (gid < BB * SS) deg[gid] = 1.0f;     // self-loop contributes +1
    if (gid < BB * HH) zbuf[gid] = 0.0f;
}

__global__ void k_deg(const int* __restrict__ eidx, const float* __restrict__ ew,
                      float* __restrict__ deg) {
    int gid = blockIdx.x * blockDim.x + threadIdx.x;
    if (gid >= BB * EE) return;
    int b = gid >> 11;            // E = 2048
    int e = gid & (EE - 1);
    int d = eidx[(size_t)b * 2 * EE + EE + e];
    atomicAdd(&deg[b * SS + d], ew[(size_t)b * EE + e]);
}

// q = (mean of h at aspect positions) @ W_span + b_span   [wave-split matvec]
__global__ __launch_bounds__(320) void k_q(const float* __restrict__ h, const int* __restrict__ ap,
                                           const float* __restrict__ W_span, const float* __restrict__ b_span,
                                           float* __restrict__ qbuf) {
    int b = blockIdx.x;
    int tid = threadIdx.x, lane = tid & 63, w = tid >> 6;
    __shared__ float av[HH];
    __shared__ float psum[5][PSTRIDE];
    const float* hb = h + (size_t)b * SS * HH;
    for (int j = tid; j < HH; j += 320) {
        float s = 0.f;
        for (int a = 0; a < AA; ++a) s += hb[(size_t)ap[b * AA + a] * HH + j];
        av[j] = s * (1.0f / AA);
    }
    __syncthreads();
    float acc[5] = {0.f, 0.f, 0.f, 0.f, 0.f};
    for (int ii = 0; ii < 60; ++ii) {
        int i = w * 60 + ii;
        float sv = av[i];
        const float* wr = W_span + (size_t)i * HH;
#pragma unroll
        for (int k = 0; k < 5; ++k) { int j = lane + 64 * k; if (j < HH) acc[k] = fmaf(sv, wr[j], acc[k]); }
    }
#pragma unroll
    for (int k = 0; k < 5; ++k) { int j = lane + 64 * k; if (j < HH) psum[w][j] = acc[k]; }
    __syncthreads();
    for (int j = tid; j < HH; j += 320)
        qbuf[b * HH + j] = b_span[j] + psum[0][j] + psum[1][j] + psum[2][j] + psum[3][j] + psum[4][j];
}

// online-softmax partials: one pass over h. Each block: 128 rows, 4 waves x 32 rows.
__global__ __launch_bounds__(256) void k_span_part(const float* __restrict__ h,
                                                   const float* __restrict__ qbuf,
                                                   float* __restrict__ part) {
    int b = blockIdx.x / NB, nb = blockIdx.x % NB;
    int tid = threadIdx.x, lane = tid & 63, w = tid >> 6;
    const float* hb = h + (size_t)b * SS * HH;
    const float* qb = qbuf + b * HH;
    float qr[5];
#pragma unroll
    for (int k = 0; k < 5; ++k) { int idx = lane + 64 * k; qr[k] = (idx < HH) ? qb[idx] : 0.f; }
    float m = -INFINITY, l = 0.f;
    float acc[5] = {0.f, 0.f, 0.f, 0.f, 0.f};
    int row0 = nb * (SS / NB) + w * 32;
    for (int t = 0; t < 32; ++t) {
        const float* hr = hb + (size_t)(row0 + t) * HH;
        float hv[5]; float pd = 0.f;
#pragma unroll
        for (int k = 0; k < 5; ++k) {
            int idx = lane + 64 * k;
            hv[k] = (idx < HH) ? hr[idx] : 0.f;
            pd += hv[k] * qr[k];
        }
#pragma unroll
        for (int off = 32; off > 0; off >>= 1) pd += __shfl_xor(pd, off, 64);
        float mn = fmaxf(m, pd);
        float sc = __expf(m - mn);     // exp(-inf)=0 handles first row
        float p  = __expf(pd - mn);
        l = l * sc + p;
#pragma unroll
        for (int k = 0; k < 5; ++k) acc[k] = acc[k] * sc + p * hv[k];
        m = mn;
    }
    __shared__ float sm[4], sl[4], sacc[4][PSTRIDE];
#pragma unroll
    for (int k = 0; k < 5; ++k) { int idx = lane + 64 * k; if (idx < HH) sacc[w][idx] = acc[k]; }
    if (lane == 0) { sm[w] = m; sl[w] = l; }
    __syncthreads();
    float M = fmaxf(fmaxf(sm[0], sm[1]), fmaxf(sm[2], sm[3]));
    float* pb = part + ((size_t)b * NB + nb) * PSTRIDE;
    for (int j = tid; j < HH; j += 256) {
        float s = 0.f;
#pragma unroll
        for (int ww = 0; ww < 4; ++ww) s += sacc[ww][j] * __expf(sm[ww] - M);
        pb[j] = s;
    }
    if (tid == 0) {
        float L = 0.f;
        for (int ww = 0; ww < 4; ++ww) L += sl[ww] * __expf(sm[ww] - M);
        pb[300] = L; pb[301] = M;
    }
}

__global__ __launch_bounds__(256) void k_span_final(const float* __restrict__ part,
                                                    float* __restrict__ span) {
    int b = blockIdx.x; int tid = threadIdx.x;
    const float* pb = part + (size_t)b * NB * PSTRIDE;
    float M = -INFINITY;
    for (int nb = 0; nb < NB; ++nb) M = fmaxf(M, pb[nb * PSTRIDE + 301]);
    float L = 0.f;
    for (int nb = 0; nb < NB; ++nb) L += pb[nb * PSTRIDE + 300] * __expf(pb[nb * PSTRIDE + 301] - M);
    float invL = 1.0f / L;
    for (int j = tid; j < HH; j += blockDim.x) {
        float s = 0.f;
        for (int nb = 0; nb < NB; ++nb) s += pb[nb * PSTRIDE + j] * __expf(pb[nb * PSTRIDE + 301] - M);
        span[b * HH + j] = s * invL;
    }
}

// Output-sparse GCN, layer-1 stage. Per (sample, aspect) block:
//   dense out-cone weights w[1024] (one E-scan, dedupes), compact,
//   chunked gather of u_r rows (one E-scan per 16-row chunk, ballot-cooperative),
//   wave-split W1 matvec + relu per cone row, z accumulated; z -> zbuf (global atomic).
// syn = b2 + (sum_a z_a / A) @ W2 is done once per sample in k_syn2 (linearity).
__global__ __launch_bounds__(320) void k_syn1(const float* __restrict__ h, const int* __restrict__ eidx,
                                              const float* __restrict__ ew, const int* __restrict__ ap,
                                              const float* __restrict__ W1, const float* __restrict__ b1,
                                              const float* __restrict__ deg, float* __restrict__ zbuf) {
    int b = blockIdx.x / AA, a = blockIdx.x % AA;
    int tid = threadIdx.x, lane = tid & 63, w = tid >> 6;
    const int* srcA = eidx + (size_t)b * 2 * EE;
    const int* dstA = srcA + EE;
    const float* ewb  = ew + (size_t)b * EE;
    const float* hb   = h + (size_t)b * SS * HH;
    const float* degb = deg + (size_t)b * SS;

    __shared__ float wv[SS];          // dense out-cone weights
    __shared__ int   idxmap[SS];      // row -> chunk slot
    __shared__ int   rl[SS];          // compacted cone rows
    __shared__ float cf[SS];          // their weights
    __shared__ float U[CH][HH];       // gathered conv-input rows
    __shared__ float psum[5][PSTRIDE];
    __shared__ float z[HH];
    __shared__ int   cnt;

    int pos = ap[b * AA + a];
    for (int r = tid; r < SS; r += 320) wv[r] = 0.f;
    for (int j = tid; j < HH; j += 320) z[j] = 0.f;
    if (tid == 0) cnt = 0;
    __syncthreads();

    // Phase 1: out-cone weights (self + in-edges of pos), dedup via dense accumulate
    float dip = rsqrtf(degb[pos]);
    if (tid == 0) atomicAdd(&wv[pos], 1.0f / degb[pos]);
    for (int e = tid; e < EE; e += 320) {
        if (dstA[e] == pos)
            atomicAdd(&wv[srcA[e]], rsqrtf(degb[srcA[e]]) * ewb[e] * dip);
    }
    __syncthreads();

    // Phase 2: compact
    for (int r = tid; r < SS; r += 320) {
        float c = wv[r];
        if (c > 0.f) { int k = atomicAdd(&cnt, 1); rl[k] = r; cf[k] = c; }
    }
    __syncthreads();
    int nc = cnt;

    // Phase 3: chunks of cone rows
    for (int c0 = 0; c0 < nc; c0 += CH) {
        int ch = min(CH, nc - c0);
        // idxmap + U self-init
        for (int r = tid; r < SS; r += 320) idxmap[r] = -1;
        __syncthreads();
        if (tid < ch) idxmap[rl[c0 + tid]] = tid;
        __syncthreads();
        for (int t = 0; t < ch; ++t) {
            int r = rl[c0 + t]; float sc = 1.0f / degb[r];
            const float* hr = hb + (size_t)r * HH;
            for (int j = tid; j < HH; j += 320) U[t][j] = hr[j] * sc;
        }
        __syncthreads();
        // one E-scan: gather in-edge contributions into U (ballot-cooperative)
        for (int e0 = 0; e0 < EE; e0 += 320) {
            int e = e0 + tid;
            bool hit = false; int t = -1, s = 0; float co = 0.f;
            if (e < EE) {
                int d = dstA[e];
                t = idxmap[d];
                if (t >= 0) {
                    s = srcA[e];
                    co = rsqrtf(degb[s]) * ewb[e] * rsqrtf(degb[d]);
                    hit = true;
                }
            }
            unsigned long long mask = __ballot(hit);
            while (mask) {
                int l = __ffsll((unsigned long long)mask) - 1; mask &= mask - 1;
                int ts = __shfl(t, l); int ss = __shfl(s, l); float cs = __shfl(co, l);
                const float* hr = hb + (size_t)ss * HH;
#pragma unroll
                for (int k = 0; k < 5; ++k) { int j = lane + 64 * k; if (j < HH) atomicAdd(&U[ts][j], cs * hr[j]); }
            }
        }
        __syncthreads();
        // wave-split matvec per chunk row: z += cf * relu(b1 + U[t] @ W1)
        for (int t = 0; t < ch; ++t) {
            float acc[5] = {0.f, 0.f, 0.f, 0.f, 0.f};
            for (int ii = 0; ii < 60; ++ii) {
                int i = w * 60 + ii;
                float sv = U[t][i];
                const float* wr = W1 + (size_t)i * HH;
#pragma unroll
                for (int k = 0; k < 5; ++k) { int j = lane + 64 * k; if (j < HH) acc[k] = fmaf(sv, wr[j], acc[k]); }
            }
#pragma unroll
            for (int k = 0; k < 5; ++k) { int j = lane + 64 * k; if (j < HH) psum[w][j] = acc[k]; }
            __syncthreads();
            float cr = cf[c0 + t];
            for (int j = tid; j < HH; j += 320) {
                float v = b1[j] + psum[0][j] + psum[1][j] + psum[2][j] + psum[3][j] + psum[4][j];
                z[j] += cr * fmaxf(v, 0.f);
            }
            __syncthreads();
        }
    }
    // Phase 4: z -> zbuf (accumulated across aspects)
    for (int j = tid; j < HH; j += 320) atomicAdd(&zbuf[b * HH + j], z[j]);
}

// syn = b2 + (zsum / A) @ W2   [per sample, wave-split matvec]
__global__ __launch_bounds__(320) void k_syn2(const float* __restrict__ zbuf,
                                              const float* __restrict__ W2, const float* __restrict__ b2,
                                              float* __restrict__ syn) {
    int b = blockIdx.x;
    int tid = threadIdx.x, lane = tid & 63, w = tid >> 6;
    __shared__ float zl[HH];
    __shared__ float psum[5][PSTRIDE];
    for (int j = tid; j < HH; j += 320) zl[j] = zbuf[b * HH + j];
    __syncthreads();
    float acc[5] = {0.f, 0.f, 0.f, 0.f, 0.f};
    for (int ii = 0; ii < 60; ++ii) {
        int i = w * 60 + ii;
        float sv = zl[i];
        const float* wr = W2 + (size_t)i * HH;
#pragma unroll
        for (int k = 0; k < 5; ++k) { int j = lane + 64 * k; if (j < HH) acc[k] = fmaf(sv, wr[j], acc[k]); }
    }
#pragma unroll
    for (int k = 0; k < 5; ++k) { int j = lane + 64 * k; if (j < HH) psum[w][j] = acc[k]; }
    __syncthreads();
    for (int j = tid; j < HH; j += 320)
        syn[b * HH + j] = b2[j] + (psum[0][j] + psum[1][j] + psum[2][j] + psum[3][j] + psum[4][j]) * (1.0f / AA);
}

__global__ __launch_bounds__(320) void k_head(const float* __restrict__ span, const float* __restrict__ syn,
                                              const float* __restrict__ W_gate, const float* __restrict__ b_gate,
                                              const float* __restrict__ W_cls, const float* __restrict__ b_cls,
                                              float* __restrict__ out) {
    int b = blockIdx.x;
    int tid = threadIdx.x, lane = tid & 63, w = tid >> 6;
    __shared__ float ssp[HH], ssy[HH];
    __shared__ float psum[5][PSTRIDE];
    __shared__ float csum[5][CC];
    for (int j = tid; j < HH; j += 320) { ssp[j] = span[b * HH + j]; ssy[j] = syn[b * HH + j]; }
    __syncthreads();
    // gate matvec over 600 concat inputs, wave-split (120 i's per wave)
    float acc[5] = {0.f, 0.f, 0.f, 0.f, 0.f};
    for (int ii = 0; ii < 120; ++ii) {
        int i = w * 120 + ii;
        float sv = (i < HH) ? ssp[i] : ssy[i - HH];
        const float* wr = W_gate + (size_t)i * HH;
#pragma unroll
        for (int k = 0; k < 5; ++k) { int j = lane + 64 * k; if (j < HH) acc[k] = fmaf(sv, wr[j], acc[k]); }
    }
#pragma unroll
    for (int k = 0; k < 5; ++k) { int j = lane + 64 * k; if (j < HH) psum[w][j] = acc[k]; }
    __syncthreads();
    // epilogue: gate, fuse, cls (shuffle reduce)
    float c0 = 0.f, c1 = 0.f, c2 = 0.f;
    int j = tid;
    if (j < HH) {
        float g = 1.0f / (1.0f + __expf(-(b_gate[j] + psum[0][j] + psum[1][j] + psum[2][j] + psum[3][j] + psum[4][j])));
        float f = g * ssy[j] + (1.0f - g) * ssp[j];
        c0 = f * W_cls[j * CC + 0];
        c1 = f * W_cls[j * CC + 1];
        c2 = f * W_cls[j * CC + 2];
    }
#pragma unroll
    for (int off = 32; off > 0; off >>= 1) {
        c0 += __shfl_xor(c0, off, 64);
        c1 += __shfl_xor(c1, off, 64);
        c2 += __shfl_xor(c2, off, 64);
    }
    if (lane == 0) { csum[w][0] = c0; csum[w][1] = c1; csum[w][2] = c2; }
    __syncthreads();
    if (tid < CC) {
        float s = b_cls[tid];
        for (int ww = 0; ww < 5; ++ww) s += csum[ww][tid];
        out[b * CC + tid] = s;
    }
}

extern "C" void kernel_launch(void* const* d_in, const int* in_sizes, int n_in,
                              void* d_out, int out_size, void* d_ws, size_t ws_size,
                              hipStream_t stream) {
    const float* h      = (const float*)d_in[0];
    const int*   eidx   = (const int*)d_in[1];
    const float* ew     = (const float*)d_in[2];
    const int*   ap     = (const int*)d_in[3];
    const float* W_span = (const float*)d_in[4];
    const float* b_span = (const float*)d_in[5];
    const float* W1     = (const float*)d_in[6];
    const float* b1     = (const float*)d_in[7];
    const float* W2     = (const float*)d_in[8];
    const float* b2     = (const float*)d_in[9];
    const float* W_gate = (const float*)d_in[10];
    const float* b_gate = (const float*)d_in[11];
    const float* W_cls  = (const float*)d_in[12];
    const float* b_cls  = (const float*)d_in[13];
    float* out = (float*)d_out;

    float* w    = (float*)d_ws;
    float* deg  = w;                         // B*S
    float* qbuf = deg + BB * SS;             // B*H
    float* part = qbuf + BB * HH;            // B*NB*PSTRIDE
    float* span = part + BB * NB * PSTRIDE;  // B*H
    float* zbuf = span + BB * HH;            // B*H
    float* syn  = zbuf + BB * HH;            // B*H

    hipLaunchKernelGGL(k_init, dim3(512), dim3(256), 0, stream, deg, zbuf);
    hipLaunchKernelGGL(k_deg, dim3((BB * EE + 255) / 256), dim3(256), 0, stream, eidx, ew, deg);
    hipLaunchKernelGGL(k_q, dim3(BB), dim3(320), 0, stream, h, ap, W_span, b_span, qbuf);
    hipLaunchKernelGGL(k_span_part, dim3(BB * NB), dim3(256), 0, stream, h, qbuf, part);
    hipLaunchKernelGGL(k_span_final, dim3(BB), dim3(256), 0, stream, part, span);
    hipLaunchKernelGGL(k_syn1, dim3(BB * AA), dim3(320), 0, stream, h, eidx, ew, ap, W1, b1, deg, zbuf);
    hipLaunchKernelGGL(k_syn2, dim3(BB), dim3(320), 0, stream, zbuf, W2, b2, syn);
    hipLaunchKernelGGL(k_head, dim3(BB), dim3(320), 0, stream, span, syn, W_gate, b_gate, W_cls, b_cls, out);
}

// Round 5
// 530.282 us; speedup vs baseline: 1.1418x; 1.1418x over previous
//
#include <hip/hip_runtime.h>
#include <math.h>

#define BB 128
#define SS 1024
#define EE 2048
#define HH 300
#define AA 5
#define CC 3
#define NB 8          // softmax partial blocks per sample
#define PSTRIDE 304   // partial record: 300 acc + l + m (padded)
#define KROW 32       // row-blocks per sample (strided loop covers worst case)

// ---------------- ws layout ----------------
// floats: deg [B*S] | qbuf [B*H] | part [B*NB*PSTRIDE] | span [B*H] | zbuf [B*H] | syn [B*H] | clist [B*S]
// ints:   cntg [B] | rowlist [B*S]

__global__ void k_init(float* deg, float* zbuf) {
    int gid = blockIdx.x * blockDim.x + threadIdx.x;
    if (gid < BB * SS) deg[gid] = 1.0f;     // self-loop contributes +1
    if (gid < BB * HH) zbuf[gid] = 0.0f;
}

__global__ void k_deg(const int* __restrict__ eidx, const float* __restrict__ ew,
                      float* __restrict__ deg) {
    int gid = blockIdx.x * blockDim.x + threadIdx.x;
    if (gid >= BB * EE) return;
    int b = gid >> 11;            // E = 2048
    int e = gid & (EE - 1);
    int d = eidx[(size_t)b * 2 * EE + EE + e];
    atomicAdd(&deg[b * SS + d], ew[(size_t)b * EE + e]);
}

// q = (mean of h at aspect positions) @ W_span + b_span   [wave-split matvec]
__global__ __launch_bounds__(320) void k_q(const float* __restrict__ h, const int* __restrict__ ap,
                                           const float* __restrict__ W_span, const float* __restrict__ b_span,
                                           float* __restrict__ qbuf) {
    int b = blockIdx.x;
    int tid = threadIdx.x, lane = tid & 63, w = tid >> 6;
    __shared__ float av[HH];
    __shared__ float psum[5][PSTRIDE];
    const float* hb = h + (size_t)b * SS * HH;
    for (int j = tid; j < HH; j += 320) {
        float s = 0.f;
        for (int a = 0; a < AA; ++a) s += hb[(size_t)ap[b * AA + a] * HH + j];
        av[j] = s * (1.0f / AA);
    }
    __syncthreads();
    float acc[5] = {0.f, 0.f, 0.f, 0.f, 0.f};
    for (int ii = 0; ii < 60; ++ii) {
        int i = w * 60 + ii;
        float sv = av[i];
        const float* wr = W_span + (size_t)i * HH;
#pragma unroll
        for (int k = 0; k < 5; ++k) { int j = lane + 64 * k; if (j < HH) acc[k] = fmaf(sv, wr[j], acc[k]); }
    }
#pragma unroll
    for (int k = 0; k < 5; ++k) { int j = lane + 64 * k; if (j < HH) psum[w][j] = acc[k]; }
    __syncthreads();
    for (int j = tid; j < HH; j += 320)
        qbuf[b * HH + j] = b_span[j] + psum[0][j] + psum[1][j] + psum[2][j] + psum[3][j] + psum[4][j];
}

// online-softmax partials: one pass over h. Each block: 128 rows, 4 waves x 32 rows.
__global__ __launch_bounds__(256) void k_span_part(const float* __restrict__ h,
                                                   const float* __restrict__ qbuf,
                                                   float* __restrict__ part) {
    int b = blockIdx.x / NB, nb = blockIdx.x % NB;
    int tid = threadIdx.x, lane = tid & 63, w = tid >> 6;
    const float* hb = h + (size_t)b * SS * HH;
    const float* qb = qbuf + b * HH;
    float qr[5];
#pragma unroll
    for (int k = 0; k < 5; ++k) { int idx = lane + 64 * k; qr[k] = (idx < HH) ? qb[idx] : 0.f; }
    float m = -INFINITY, l = 0.f;
    float acc[5] = {0.f, 0.f, 0.f, 0.f, 0.f};
    int row0 = nb * (SS / NB) + w * 32;
    for (int t = 0; t < 32; ++t) {
        const float* hr = hb + (size_t)(row0 + t) * HH;
        float hv[5]; float pd = 0.f;
#pragma unroll
        for (int k = 0; k < 5; ++k) {
            int idx = lane + 64 * k;
            hv[k] = (idx < HH) ? hr[idx] : 0.f;
            pd += hv[k] * qr[k];
        }
#pragma unroll
        for (int off = 32; off > 0; off >>= 1) pd += __shfl_xor(pd, off, 64);
        float mn = fmaxf(m, pd);
        float sc = __expf(m - mn);     // exp(-inf)=0 handles first row
        float p  = __expf(pd - mn);
        l = l * sc + p;
#pragma unroll
        for (int k = 0; k < 5; ++k) acc[k] = acc[k] * sc + p * hv[k];
        m = mn;
    }
    __shared__ float sm[4], sl[4], sacc[4][PSTRIDE];
#pragma unroll
    for (int k = 0; k < 5; ++k) { int idx = lane + 64 * k; if (idx < HH) sacc[w][idx] = acc[k]; }
    if (lane == 0) { sm[w] = m; sl[w] = l; }
    __syncthreads();
    float M = fmaxf(fmaxf(sm[0], sm[1]), fmaxf(sm[2], sm[3]));
    float* pb = part + ((size_t)b * NB + nb) * PSTRIDE;
    for (int j = tid; j < HH; j += 256) {
        float s = 0.f;
#pragma unroll
        for (int ww = 0; ww < 4; ++ww) s += sacc[ww][j] * __expf(sm[ww] - M);
        pb[j] = s;
    }
    if (tid == 0) {
        float L = 0.f;
        for (int ww = 0; ww < 4; ++ww) L += sl[ww] * __expf(sm[ww] - M);
        pb[300] = L; pb[301] = M;
    }
}

__global__ __launch_bounds__(256) void k_span_final(const float* __restrict__ part,
                                                    float* __restrict__ span) {
    int b = blockIdx.x; int tid = threadIdx.x;
    const float* pb = part + (size_t)b * NB * PSTRIDE;
    float M = -INFINITY;
    for (int nb = 0; nb < NB; ++nb) M = fmaxf(M, pb[nb * PSTRIDE + 301]);
    float L = 0.f;
    for (int nb = 0; nb < NB; ++nb) L += pb[nb * PSTRIDE + 300] * __expf(pb[nb * PSTRIDE + 301] - M);
    float invL = 1.0f / L;
    for (int j = tid; j < HH; j += blockDim.x) {
        float s = 0.f;
        for (int nb = 0; nb < NB; ++nb) s += pb[nb * PSTRIDE + j] * __expf(pb[nb * PSTRIDE + 301] - M);
        span[b * HH + j] = s * invL;
    }
}

// Per sample: deduped union of aspect out-cones with combined coefficients.
// C_r = sum_a [ (r==pos_a)/deg_r + sum_{e: dst=pos_a, src=r} rsqrt(deg_r)*ew*rsqrt(deg_pos_a) ]
// (relu argument is aspect-independent, so aspects combine linearly BEFORE relu)
__global__ __launch_bounds__(256) void k_prep(const int* __restrict__ eidx, const float* __restrict__ ew,
                                              const int* __restrict__ ap, const float* __restrict__ deg,
                                              int* __restrict__ cntg, int* __restrict__ rowlist,
                                              float* __restrict__ clist) {
    int b = blockIdx.x; int tid = threadIdx.x;
    __shared__ float C[SS];
    __shared__ int poss[AA]; __shared__ float dinvp[AA];
    __shared__ int cnt_l;
    const int* srcA = eidx + (size_t)b * 2 * EE;
    const int* dstA = srcA + EE;
    const float* ewb  = ew + (size_t)b * EE;
    const float* degb = deg + (size_t)b * SS;
    for (int r = tid; r < SS; r += 256) C[r] = 0.f;
    if (tid == 0) cnt_l = 0;
    if (tid < AA) poss[tid] = ap[b * AA + tid];
    __syncthreads();
    if (tid < AA) {
        dinvp[tid] = rsqrtf(degb[poss[tid]]);
        atomicAdd(&C[poss[tid]], 1.0f / degb[poss[tid]]);   // self-loop term per aspect
    }
    __syncthreads();
    for (int e = tid; e < EE; e += 256) {
        int d = dstA[e];
        float co = 0.f;
#pragma unroll
        for (int a = 0; a < AA; ++a) if (d == poss[a]) co += dinvp[a];
        if (co > 0.f) {
            int s = srcA[e];
            atomicAdd(&C[s], rsqrtf(degb[s]) * ewb[e] * co);
        }
    }
    __syncthreads();
    for (int r = tid; r < SS; r += 256) {
        float c = C[r];
        if (c > 0.f) { int k = atomicAdd(&cnt_l, 1); rowlist[(size_t)b * SS + k] = r; clist[(size_t)b * SS + k] = c; }
    }
    __syncthreads();
    if (tid == 0) cntg[b] = cnt_l;
}

// One block per cone row: u_r = h_r/deg_r + sum_in-edges norm*h_src (LDS),
// wave-split W1 matvec, zbuf[b] += C_r * relu(b1 + u_r@W1).
__global__ __launch_bounds__(320) void k_row(const float* __restrict__ h, const int* __restrict__ eidx,
                                             const float* __restrict__ ew, const float* __restrict__ deg,
                                             const int* __restrict__ cntg, const int* __restrict__ rowlist,
                                             const float* __restrict__ clist,
                                             const float* __restrict__ W1, const float* __restrict__ b1,
                                             float* __restrict__ zbuf) {
    int b = blockIdx.x;
    int tid = threadIdx.x, lane = tid & 63, w = tid >> 6;
    int cnt = cntg[b];
    const int* srcA = eidx + (size_t)b * 2 * EE;
    const int* dstA = srcA + EE;
    const float* ewb  = ew + (size_t)b * EE;
    const float* degb = deg + (size_t)b * SS;
    const float* hb   = h + (size_t)b * SS * HH;
    __shared__ float u[HH];
    __shared__ float psum[5][PSTRIDE];
    for (int k = blockIdx.y; k < cnt; k += KROW) {
        int r = rowlist[(size_t)b * SS + k];
        float Cr = clist[(size_t)b * SS + k];
        float dr = degb[r];
        float dinvr = rsqrtf(dr);
        for (int j = tid; j < HH; j += 320) u[j] = hb[(size_t)r * HH + j] * (1.0f / dr);
        __syncthreads();
        for (int e0 = 0; e0 < EE; e0 += 320) {
            int e = e0 + tid;
            bool hit = false; int s = 0; float co = 0.f;
            if (e < EE && dstA[e] == r) {
                s = srcA[e];
                co = rsqrtf(degb[s]) * ewb[e] * dinvr;
                hit = true;
            }
            unsigned long long mask = __ballot(hit);
            while (mask) {
                int l = __ffsll(mask) - 1; mask &= mask - 1;
                int ss2 = __shfl(s, l); float cs = __shfl(co, l);
                const float* hr = hb + (size_t)ss2 * HH;
#pragma unroll
                for (int kk = 0; kk < 5; ++kk) { int j = lane + 64 * kk; if (j < HH) atomicAdd(&u[j], cs * hr[j]); }
            }
        }
        __syncthreads();
        float acc[5] = {0.f, 0.f, 0.f, 0.f, 0.f};
        for (int ii = 0; ii < 60; ++ii) {
            int i = w * 60 + ii;
            float sv = u[i];
            const float* wr = W1 + (size_t)i * HH;
#pragma unroll
            for (int kk = 0; kk < 5; ++kk) { int j = lane + 64 * kk; if (j < HH) acc[kk] = fmaf(sv, wr[j], acc[kk]); }
        }
#pragma unroll
        for (int kk = 0; kk < 5; ++kk) { int j = lane + 64 * kk; if (j < HH) psum[w][j] = acc[kk]; }
        __syncthreads();
        for (int j = tid; j < HH; j += 320) {
            float y = b1[j] + psum[0][j] + psum[1][j] + psum[2][j] + psum[3][j] + psum[4][j];
            atomicAdd(&zbuf[b * HH + j], Cr * fmaxf(y, 0.f));
        }
        __syncthreads();
    }
}

// syn = b2 + (zsum / A) @ W2   [per sample, wave-split matvec]
__global__ __launch_bounds__(320) void k_syn2(const float* __restrict__ zbuf,
                                              const float* __restrict__ W2, const float* __restrict__ b2,
                                              float* __restrict__ syn) {
    int b = blockIdx.x;
    int tid = threadIdx.x, lane = tid & 63, w = tid >> 6;
    __shared__ float zl[HH];
    __shared__ float psum[5][PSTRIDE];
    for (int j = tid; j < HH; j += 320) zl[j] = zbuf[b * HH + j];
    __syncthreads();
    float acc[5] = {0.f, 0.f, 0.f, 0.f, 0.f};
    for (int ii = 0; ii < 60; ++ii) {
        int i = w * 60 + ii;
        float sv = zl[i];
        const float* wr = W2 + (size_t)i * HH;
#pragma unroll
        for (int k = 0; k < 5; ++k) { int j = lane + 64 * k; if (j < HH) acc[k] = fmaf(sv, wr[j], acc[k]); }
    }
#pragma unroll
    for (int k = 0; k < 5; ++k) { int j = lane + 64 * k; if (j < HH) psum[w][j] = acc[k]; }
    __syncthreads();
    for (int j = tid; j < HH; j += 320)
        syn[b * HH + j] = b2[j] + (psum[0][j] + psum[1][j] + psum[2][j] + psum[3][j] + psum[4][j]) * (1.0f / AA);
}

__global__ __launch_bounds__(320) void k_head(const float* __restrict__ span, const float* __restrict__ syn,
                                              const float* __restrict__ W_gate, const float* __restrict__ b_gate,
                                              const float* __restrict__ W_cls, const float* __restrict__ b_cls,
                                              float* __restrict__ out) {
    int b = blockIdx.x;
    int tid = threadIdx.x, lane = tid & 63, w = tid >> 6;
    __shared__ float ssp[HH], ssy[HH];
    __shared__ float psum[5][PSTRIDE];
    __shared__ float csum[5][CC];
    for (int j = tid; j < HH; j += 320) { ssp[j] = span[b * HH + j]; ssy[j] = syn[b * HH + j]; }
    __syncthreads();
    float acc[5] = {0.f, 0.f, 0.f, 0.f, 0.f};
    for (int ii = 0; ii < 120; ++ii) {
        int i = w * 120 + ii;
        float sv = (i < HH) ? ssp[i] : ssy[i - HH];
        const float* wr = W_gate + (size_t)i * HH;
#pragma unroll
        for (int k = 0; k < 5; ++k) { int j = lane + 64 * k; if (j < HH) acc[k] = fmaf(sv, wr[j], acc[k]); }
    }
#pragma unroll
    for (int k = 0; k < 5; ++k) { int j = lane + 64 * k; if (j < HH) psum[w][j] = acc[k]; }
    __syncthreads();
    float c0 = 0.f, c1 = 0.f, c2 = 0.f;
    int j = tid;
    if (j < HH) {
        float g = 1.0f / (1.0f + __expf(-(b_gate[j] + psum[0][j] + psum[1][j] + psum[2][j] + psum[3][j] + psum[4][j])));
        float f = g * ssy[j] + (1.0f - g) * ssp[j];
        c0 = f * W_cls[j * CC + 0];
        c1 = f * W_cls[j * CC + 1];
        c2 = f * W_cls[j * CC + 2];
    }
#pragma unroll
    for (int off = 32; off > 0; off >>= 1) {
        c0 += __shfl_xor(c0, off, 64);
        c1 += __shfl_xor(c1, off, 64);
        c2 += __shfl_xor(c2, off, 64);
    }
    if (lane == 0) { csum[w][0] = c0; csum[w][1] = c1; csum[w][2] = c2; }
    __syncthreads();
    if (tid < CC) {
        float s = b_cls[tid];
        for (int ww = 0; ww < 5; ++ww) s += csum[ww][tid];
        out[b * CC + tid] = s;
    }
}

extern "C" void kernel_launch(void* const* d_in, const int* in_sizes, int n_in,
                              void* d_out, int out_size, void* d_ws, size_t ws_size,
                              hipStream_t stream) {
    const float* h      = (const float*)d_in[0];
    const int*   eidx   = (const int*)d_in[1];
    const float* ew     = (const float*)d_in[2];
    const int*   ap     = (const int*)d_in[3];
    const float* W_span = (const float*)d_in[4];
    const float* b_span = (const float*)d_in[5];
    const float* W1     = (const float*)d_in[6];
    const float* b1     = (const float*)d_in[7];
    const float* W2     = (const float*)d_in[8];
    const float* b2     = (const float*)d_in[9];
    const float* W_gate = (const float*)d_in[10];
    const float* b_gate = (const float*)d_in[11];
    const float* W_cls  = (const float*)d_in[12];
    const float* b_cls  = (const float*)d_in[13];
    float* out = (float*)d_out;

    float* w     = (float*)d_ws;
    float* deg   = w;                         // B*S
    float* qbuf  = deg + BB * SS;             // B*H
    float* part  = qbuf + BB * HH;            // B*NB*PSTRIDE
    float* span  = part + BB * NB * PSTRIDE;  // B*H
    float* zbuf  = span + BB * HH;            // B*H
    float* syn   = zbuf + BB * HH;            // B*H
    float* clist = syn + BB * HH;             // B*S
    int*   cntg    = (int*)(clist + BB * SS); // B
    int*   rowlist = cntg + BB;               // B*S

    hipLaunchKernelGGL(k_init, dim3(512), dim3(256), 0, stream, deg, zbuf);
    hipLaunchKernelGGL(k_deg, dim3((BB * EE + 255) / 256), dim3(256), 0, stream, eidx, ew, deg);
    hipLaunchKernelGGL(k_q, dim3(BB), dim3(320), 0, stream, h, ap, W_span, b_span, qbuf);
    hipLaunchKernelGGL(k_span_part, dim3(BB * NB), dim3(256), 0, stream, h, qbuf, part);
    hipLaunchKernelGGL(k_span_final, dim3(BB), dim3(256), 0, stream, part, span);
    hipLaunchKernelGGL(k_prep, dim3(BB), dim3(256), 0, stream, eidx, ew, ap, deg, cntg, rowlist, clist);
    hipLaunchKernelGGL(k_row, dim3(BB, KROW), dim3(320), 0, stream, h, eidx, ew, deg, cntg, rowlist, clist, W1, b1, zbuf);
    hipLaunchKernelGGL(k_syn2, dim3(BB), dim3(320), 0, stream, zbuf, W2, b2, syn);
    hipLaunchKernelGGL(k_head, dim3(BB), dim3(320), 0, stream, span, syn, W_gate, b_gate, W_cls, b_cls, out);
}

// Round 7
// 344.061 us; speedup vs baseline: 1.7597x; 1.5412x over previous
//
#include <hip/hip_runtime.h>
#include <math.h>

#define BB 128
#define SS 1024
#define EE 2048
#define HH 300
#define AA 5
#define CC 3
#define NB 16         // softmax partial blocks per sample
#define PSTRIDE 304   // partial record: 300 acc + l + m (padded)
#define KROWG 8       // y-grid for k_row groups
#define RB 4          // cone rows per k_row block

// ---------------- ws layout ----------------
// floats: deg[B*S] | qbuf[B*H] | part[B*NB*PSTRIDE] | span[B*H] | zbuf[B*H] | syn[B*H] | gate[B*H] | clist[B*S]
// ints:   cntg[B] | rowlist[B*S]

__global__ void k_init(float* deg, float* zbuf, float* qbuf, float* gatebuf, float* syn,
                       const float* __restrict__ b_span, const float* __restrict__ b_gate,
                       const float* __restrict__ b2) {
    int gid = blockIdx.x * blockDim.x + threadIdx.x;
    if (gid < BB * SS) deg[gid] = 1.0f;     // self-loop contributes +1
    if (gid < BB * HH) {
        int j = gid % HH;
        zbuf[gid] = 0.0f;
        qbuf[gid] = b_span[j];
        gatebuf[gid] = b_gate[j];
        syn[gid] = b2[j];
    }
}

__global__ void k_deg(const int* __restrict__ eidx, const float* __restrict__ ew,
                      float* __restrict__ deg) {
    int gid = blockIdx.x * blockDim.x + threadIdx.x;
    if (gid >= BB * EE) return;
    int b = gid >> 11;            // E = 2048
    int e = gid & (EE - 1);
    int d = eidx[(size_t)b * 2 * EE + EE + e];
    atomicAdd(&deg[b * SS + d], ew[(size_t)b * EE + e]);
}

// qbuf += av @ W_span (chunk of K per block; qbuf pre-initialized with b_span)
// lane owns one output column j; 5 loads staged per group.
__global__ __launch_bounds__(320) void k_q(const float* __restrict__ h, const int* __restrict__ ap,
                                           const float* __restrict__ W_span, float* __restrict__ qbuf) {
    int b = blockIdx.x, kc = blockIdx.y;       // kc in [0,4): K-chunk of 75
    int tid = threadIdx.x, lane = tid & 63, w = tid >> 6;
    __shared__ float xs[75];
    __shared__ int aps[AA];
    const float* hb = h + (size_t)b * SS * HH;
    if (tid < AA) aps[tid] = ap[b * AA + tid];
    __syncthreads();
    for (int ii = tid; ii < 75; ii += 320) {
        int i = kc * 75 + ii;
        float s = 0.f;
#pragma unroll
        for (int a = 0; a < AA; ++a) s += hb[(size_t)aps[a] * HH + i];
        xs[ii] = s * (1.0f / AA);
    }
    __syncthreads();
    int j = w * 64 + lane;
    if (j < HH) {
        const float* Wp = W_span + (size_t)(kc * 75) * HH + j;
        float acc = 0.f;
        for (int ii = 0; ii < 75; ii += 5) {
            float wv[5];
#pragma unroll
            for (int u = 0; u < 5; ++u) wv[u] = Wp[(size_t)(ii + u) * HH];
#pragma unroll
            for (int u = 0; u < 5; ++u) acc = fmaf(xs[ii + u], wv[u], acc);
        }
        atomicAdd(&qbuf[b * HH + j], acc);
    }
}

// online-softmax partials: 2048 blocks, 4 waves x 16 rows, rows processed in pairs.
__global__ __launch_bounds__(256) void k_span_part(const float* __restrict__ h,
                                                   const float* __restrict__ qbuf,
                                                   float* __restrict__ part) {
    int b = blockIdx.x / NB, nb = blockIdx.x % NB;
    int tid = threadIdx.x, lane = tid & 63, w = tid >> 6;
    const float* hb = h + (size_t)b * SS * HH;
    const float* qb = qbuf + b * HH;
    float qr[5];
#pragma unroll
    for (int k = 0; k < 5; ++k) { int idx = lane + 64 * k; qr[k] = (idx < HH) ? qb[idx] : 0.f; }
    float m = -INFINITY, l = 0.f;
    float acc[5] = {0.f, 0.f, 0.f, 0.f, 0.f};
    int row0 = nb * (SS / NB) + w * 16;
    for (int t = 0; t < 16; t += 2) {
        const float* hr0 = hb + (size_t)(row0 + t) * HH;
        const float* hr1 = hr0 + HH;
        float hv0[5], hv1[5]; float pd0 = 0.f, pd1 = 0.f;
#pragma unroll
        for (int k = 0; k < 5; ++k) {
            int idx = lane + 64 * k;
            hv0[k] = (idx < HH) ? hr0[idx] : 0.f;
            hv1[k] = (idx < HH) ? hr1[idx] : 0.f;
            pd0 += hv0[k] * qr[k];
            pd1 += hv1[k] * qr[k];
        }
#pragma unroll
        for (int off = 32; off > 0; off >>= 1) {
            pd0 += __shfl_xor(pd0, off, 64);
            pd1 += __shfl_xor(pd1, off, 64);
        }
        float mn = fmaxf(m, fmaxf(pd0, pd1));
        float sc = __expf(m - mn);     // exp(-inf)=0 handles first pair
        float p0 = __expf(pd0 - mn);
        float p1 = __expf(pd1 - mn);
        l = l * sc + p0 + p1;
#pragma unroll
        for (int k = 0; k < 5; ++k) acc[k] = acc[k] * sc + p0 * hv0[k] + p1 * hv1[k];
        m = mn;
    }
    __shared__ float sm[4], sl[4], sacc[4][PSTRIDE];
#pragma unroll
    for (int k = 0; k < 5; ++k) { int idx = lane + 64 * k; if (idx < HH) sacc[w][idx] = acc[k]; }
    if (lane == 0) { sm[w] = m; sl[w] = l; }
    __syncthreads();
    float M = fmaxf(fmaxf(sm[0], sm[1]), fmaxf(sm[2], sm[3]));
    float* pb = part + ((size_t)b * NB + nb) * PSTRIDE;
    for (int j = tid; j < HH; j += 256) {
        float s = 0.f;
#pragma unroll
        for (int ww = 0; ww < 4; ++ww) s += sacc[ww][j] * __expf(sm[ww] - M);
        pb[j] = s;
    }
    if (tid == 0) {
        float L = 0.f;
        for (int ww = 0; ww < 4; ++ww) L += sl[ww] * __expf(sm[ww] - M);
        pb[300] = L; pb[301] = M;
    }
}

__global__ __launch_bounds__(256) void k_span_final(const float* __restrict__ part,
                                                    float* __restrict__ span) {
    int b = blockIdx.x; int tid = threadIdx.x;
    const float* pb = part + (size_t)b * NB * PSTRIDE;
    float M = -INFINITY;
    for (int nb = 0; nb < NB; ++nb) M = fmaxf(M, pb[nb * PSTRIDE + 301]);
    float L = 0.f;
    for (int nb = 0; nb < NB; ++nb) L += pb[nb * PSTRIDE + 300] * __expf(pb[nb * PSTRIDE + 301] - M);
    float invL = 1.0f / L;
    for (int j = tid; j < HH; j += blockDim.x) {
        float s = 0.f;
        for (int nb = 0; nb < NB; ++nb) s += pb[nb * PSTRIDE + j] * __expf(pb[nb * PSTRIDE + 301] - M);
        span[b * HH + j] = s * invL;
    }
}

// Per sample: deduped union of aspect out-cones with combined coefficients.
__global__ __launch_bounds__(256) void k_prep(const int* __restrict__ eidx, const float* __restrict__ ew,
                                              const int* __restrict__ ap, const float* __restrict__ deg,
                                              int* __restrict__ cntg, int* __restrict__ rowlist,
                                              float* __restrict__ clist) {
    int b = blockIdx.x; int tid = threadIdx.x;
    __shared__ float C[SS];
    __shared__ int poss[AA]; __shared__ float dinvp[AA];
    __shared__ int cnt_l;
    const int* srcA = eidx + (size_t)b * 2 * EE;
    const int* dstA = srcA + EE;
    const float* ewb  = ew + (size_t)b * EE;
    const float* degb = deg + (size_t)b * SS;
    for (int r = tid; r < SS; r += 256) C[r] = 0.f;
    if (tid == 0) cnt_l = 0;
    if (tid < AA) poss[tid] = ap[b * AA + tid];
    __syncthreads();
    if (tid < AA) {
        dinvp[tid] = rsqrtf(degb[poss[tid]]);
        atomicAdd(&C[poss[tid]], 1.0f / degb[poss[tid]]);   // self-loop term per aspect
    }
    __syncthreads();
    for (int e = tid; e < EE; e += 256) {
        int d = dstA[e];
        float co = 0.f;
#pragma unroll
        for (int a = 0; a < AA; ++a) if (d == poss[a]) co += dinvp[a];
        if (co > 0.f) {
            int s = srcA[e];
            atomicAdd(&C[s], rsqrtf(degb[s]) * ewb[e] * co);
        }
    }
    __syncthreads();
    for (int r = tid; r < SS; r += 256) {
        float c = C[r];
        if (c > 0.f) { int k = atomicAdd(&cnt_l, 1); rowlist[(size_t)b * SS + k] = r; clist[(size_t)b * SS + k] = c; }
    }
    __syncthreads();
    if (tid == 0) cntg[b] = cnt_l;
}

// RB=4 cone rows per block: build 4 u-rows in LDS (float4-packed), one W1 pass
// amortized over 4 rows, lane owns output col j, one global atomic per lane.
__global__ __launch_bounds__(320) void k_row(const float* __restrict__ h, const int* __restrict__ eidx,
                                             const float* __restrict__ ew, const float* __restrict__ deg,
                                             const int* __restrict__ cntg, const int* __restrict__ rowlist,
                                             const float* __restrict__ clist,
                                             const float* __restrict__ W1, const float* __restrict__ b1,
                                             float* __restrict__ zbuf) {
    int b = blockIdx.x;
    int tid = threadIdx.x, lane = tid & 63, w = tid >> 6;
    int cnt = cntg[b];
    int ngrp = (cnt + RB - 1) / RB;
    const int* srcA = eidx + (size_t)b * 2 * EE;
    const int* dstA = srcA + EE;
    const float* ewb  = ew + (size_t)b * EE;
    const float* degb = deg + (size_t)b * SS;
    const float* hb   = h + (size_t)b * SS * HH;
    __shared__ float4 u4v[HH];
    float* u4 = (float*)u4v;
    __shared__ int rr[RB]; __shared__ float cc[RB];
    __shared__ int nrows_s;
    for (int g = blockIdx.y; g < ngrp; g += KROWG) {
        if (tid < RB) {
            int k = g * RB + tid;
            if (k < cnt) { rr[tid] = rowlist[(size_t)b * SS + k]; cc[tid] = clist[(size_t)b * SS + k]; }
            else         { rr[tid] = rowlist[(size_t)b * SS];     cc[tid] = 0.f; }
        }
        if (tid == 0) nrows_s = min(RB, cnt - g * RB);
        __syncthreads();
        int nrows = nrows_s;
        // self-term init: u4[j*4+t] = h[rr[t]][j] / deg[rr[t]]
        for (int q = tid; q < HH * RB; q += 320) {
            int j = q >> 2, t = q & 3;
            u4[q] = hb[(size_t)rr[t] * HH + j] * (1.0f / degb[rr[t]]);
        }
        __syncthreads();
        // E-scan: gather in-edge contributions (ballot-cooperative wave adds)
        for (int e0 = 0; e0 < EE; e0 += 320) {
            int e = e0 + tid;
            bool hit = false; int t = -1, s = 0; float co = 0.f;
            if (e < EE) {
                int d = dstA[e];
#pragma unroll
                for (int tt = 0; tt < RB; ++tt)
                    if (tt < nrows && d == rr[tt]) t = tt;
                if (t >= 0) {
                    s = srcA[e];
                    co = rsqrtf(degb[s]) * ewb[e] * rsqrtf(degb[d]);
                    hit = true;
                }
            }
            unsigned long long mask = __ballot(hit);
            while (mask) {
                int l = __ffsll(mask) - 1; mask &= mask - 1;
                int ts = __shfl(t, l); int ss2 = __shfl(s, l); float cs = __shfl(co, l);
                const float* hs = hb + (size_t)ss2 * HH;
#pragma unroll
                for (int kk = 0; kk < 5; ++kk) {
                    int jj = lane + 64 * kk;
                    if (jj < HH) atomicAdd(&u4[jj * 4 + ts], cs * hs[jj]);
                }
            }
        }
        __syncthreads();
        // matvec: lane owns col j, W1 load shared by 4 rows
        int j = w * 64 + lane;
        if (j < HH) {
            const float* Wp = W1 + j;
            float a0 = 0.f, a1 = 0.f, a2 = 0.f, a3 = 0.f;
            for (int i0 = 0; i0 < HH; i0 += 5) {
                float wv[5];
#pragma unroll
                for (int u = 0; u < 5; ++u) wv[u] = Wp[(size_t)(i0 + u) * HH];
#pragma unroll
                for (int u = 0; u < 5; ++u) {
                    float4 xv = u4v[i0 + u];
                    a0 = fmaf(xv.x, wv[u], a0);
                    a1 = fmaf(xv.y, wv[u], a1);
                    a2 = fmaf(xv.z, wv[u], a2);
                    a3 = fmaf(xv.w, wv[u], a3);
                }
            }
            float bj = b1[j];
            float val = cc[0] * fmaxf(bj + a0, 0.f) + cc[1] * fmaxf(bj + a1, 0.f)
                      + cc[2] * fmaxf(bj + a2, 0.f) + cc[3] * fmaxf(bj + a3, 0.f);
            atomicAdd(&zbuf[b * HH + j], val);
        }
        __syncthreads();
    }
}

// syn += (zbuf/A) @ W2 (K-chunked; syn pre-initialized with b2)
__global__ __launch_bounds__(320) void k_syn2(const float* __restrict__ zbuf,
                                              const float* __restrict__ W2,
                                              float* __restrict__ syn) {
    int b = blockIdx.x, kc = blockIdx.y;       // kc in [0,4)
    int tid = threadIdx.x, lane = tid & 63, w = tid >> 6;
    __shared__ float xs[75];
    for (int ii = tid; ii < 75; ii += 320) xs[ii] = zbuf[b * HH + kc * 75 + ii];
    __syncthreads();
    int j = w * 64 + lane;
    if (j < HH) {
        const float* Wp = W2 + (size_t)(kc * 75) * HH + j;
        float acc = 0.f;
        for (int ii = 0; ii < 75; ii += 5) {
            float wv[5];
#pragma unroll
            for (int u = 0; u < 5; ++u) wv[u] = Wp[(size_t)(ii + u) * HH];
#pragma unroll
            for (int u = 0; u < 5; ++u) acc = fmaf(xs[ii + u], wv[u], acc);
        }
        atomicAdd(&syn[b * HH + j], acc * (1.0f / AA));
    }
}

// gatebuf += concat(span,syn) @ W_gate (K=600 chunked by 75; pre-init b_gate)
__global__ __launch_bounds__(320) void k_gate(const float* __restrict__ span, const float* __restrict__ syn,
                                              const float* __restrict__ W_gate,
                                              float* __restrict__ gatebuf) {
    int b = blockIdx.x, kc = blockIdx.y;       // kc in [0,8)
    int tid = threadIdx.x, lane = tid & 63, w = tid >> 6;
    __shared__ float xs[75];
    for (int ii = tid; ii < 75; ii += 320) {
        int i = kc * 75 + ii;
        xs[ii] = (i < HH) ? span[b * HH + i] : syn[b * HH + (i - HH)];
    }
    __syncthreads();
    int j = w * 64 + lane;
    if (j < HH) {
        const float* Wp = W_gate + (size_t)(kc * 75) * HH + j;
        float acc = 0.f;
        for (int ii = 0; ii < 75; ii += 5) {
            float wv[5];
#pragma unroll
            for (int u = 0; u < 5; ++u) wv[u] = Wp[(size_t)(ii + u) * HH];
#pragma unroll
            for (int u = 0; u < 5; ++u) acc = fmaf(xs[ii + u], wv[u], acc);
        }
        atomicAdd(&gatebuf[b * HH + j], acc);
    }
}

// epilogue: sigmoid gate, fuse, cls matvec (shuffle reduce), write out
__global__ __launch_bounds__(320) void k_out(const float* __restrict__ span, const float* __restrict__ syn,
                                             const float* __restrict__ gatebuf,
                                             const float* __restrict__ W_cls, const float* __restrict__ b_cls,
                                             float* __restrict__ out) {
    int b = blockIdx.x;
    int tid = threadIdx.x, lane = tid & 63, w = tid >> 6;
    __shared__ float csum[5][CC];
    float c0 = 0.f, c1 = 0.f, c2 = 0.f;
    int j = tid;
    if (j < HH) {
        float sp = span[b * HH + j], sy = syn[b * HH + j];
        float g = 1.0f / (1.0f + __expf(-gatebuf[b * HH + j]));
        float f = g * sy + (1.0f - g) * sp;
        c0 = f * W_cls[j * CC + 0];
        c1 = f * W_cls[j * CC + 1];
        c2 = f * W_cls[j * CC + 2];
    }
#pragma unroll
    for (int off = 32; off > 0; off >>= 1) {
        c0 += __shfl_xor(c0, off, 64);
        c1 += __shfl_xor(c1, off, 64);
        c2 += __shfl_xor(c2, off, 64);
    }
    if (lane == 0) { csum[w][0] = c0; csum[w][1] = c1; csum[w][2] = c2; }
    __syncthreads();
    if (tid < CC) {
        float s = b_cls[tid];
        for (int ww = 0; ww < 5; ++ww) s += csum[ww][tid];
        out[b * CC + tid] = s;
    }
}

extern "C" void kernel_launch(void* const* d_in, const int* in_sizes, int n_in,
                              void* d_out, int out_size, void* d_ws, size_t ws_size,
                              hipStream_t stream) {
    const float* h      = (const float*)d_in[0];
    const int*   eidx   = (const int*)d_in[1];
    const float* ew     = (const float*)d_in[2];
    const int*   ap     = (const int*)d_in[3];
    const float* W_span = (const float*)d_in[4];
    const float* b_span = (const float*)d_in[5];
    const float* W1     = (const float*)d_in[6];
    const float* b1     = (const float*)d_in[7];
    const float* W2     = (const float*)d_in[8];
    const float* b2     = (const float*)d_in[9];
    const float* W_gate = (const float*)d_in[10];
    const float* b_gate = (const float*)d_in[11];
    const float* W_cls  = (const float*)d_in[12];
    const float* b_cls  = (const float*)d_in[13];
    float* out = (float*)d_out;

    float* w     = (float*)d_ws;
    float* deg   = w;                         // B*S
    float* qbuf  = deg + BB * SS;             // B*H
    float* part  = qbuf + BB * HH;            // B*NB*PSTRIDE
    float* span  = part + BB * NB * PSTRIDE;  // B*H
    float* zbuf  = span + BB * HH;            // B*H
    float* syn   = zbuf + BB * HH;            // B*H
    float* gateb = syn + BB * HH;             // B*H
    float* clist = gateb + BB * HH;           // B*S
    int*   cntg    = (int*)(clist + BB * SS); // B
    int*   rowlist = cntg + BB;               // B*S

    hipLaunchKernelGGL(k_init, dim3(512), dim3(256), 0, stream, deg, zbuf, qbuf, gateb, syn, b_span, b_gate, b2);
    hipLaunchKernelGGL(k_deg, dim3((BB * EE + 255) / 256), dim3(256), 0, stream, eidx, ew, deg);
    hipLaunchKernelGGL(k_q, dim3(BB, 4), dim3(320), 0, stream, h, ap, W_span, qbuf);
    hipLaunchKernelGGL(k_span_part, dim3(BB * NB), dim3(256), 0, stream, h, qbuf, part);
    hipLaunchKernelGGL(k_span_final, dim3(BB), dim3(256), 0, stream, part, span);
    hipLaunchKernelGGL(k_prep, dim3(BB), dim3(256), 0, stream, eidx, ew, ap, deg, cntg, rowlist, clist);
    hipLaunchKernelGGL(k_row, dim3(BB, KROWG), dim3(320), 0, stream, h, eidx, ew, deg, cntg, rowlist, clist, W1, b1, zbuf);
    hipLaunchKernelGGL(k_syn2, dim3(BB, 4), dim3(320), 0, stream, zbuf, W2, syn);
    hipLaunchKernelGGL(k_gate, dim3(BB, 8), dim3(320), 0, stream, span, syn, W_gate, gateb);
    hipLaunchKernelGGL(k_out, dim3(BB), dim3(320), 0, stream, span, syn, gateb, W_cls, b_cls, out);
}